// Round 1
// baseline (880.015 us; speedup 1.0000x reference)
//
#include <hip/hip_runtime.h>
#include <hip/hip_bf16.h>

#define AS1 __attribute__((address_space(1)))
#define AS3 __attribute__((address_space(3)))

typedef __attribute__((ext_vector_type(8))) short short8;
typedef __attribute__((ext_vector_type(4))) short short4v;
typedef __attribute__((ext_vector_type(4))) float f32x4;

constexpr int S_ = 2048;
constexpr int HID_ = 4096;
constexpr int NH = 32;       // q heads
constexpr int NKH = 8;       // kv heads
constexpr int HD = 128;      // head dim
constexpr float EPS_ = 1e-5f;
constexpr float SCALE_ = 0.08838834764831845f;  // 128^-0.5

__device__ __forceinline__ short f2bf(float f) {
  __hip_bfloat16 h = __float2bfloat16(f);
  return *reinterpret_cast<short*>(&h);
}

// ---------------- fp32 -> bf16 cast (vectorized) ----------------
__global__ __launch_bounds__(256) void cast_bf16_kernel(const float4* __restrict__ src,
                                                        short4v* __restrict__ dst, int n4) {
  int i = blockIdx.x * 256 + threadIdx.x;
  if (i >= n4) return;
  float4 v = src[i];
  short4v o;
  o[0] = f2bf(v.x); o[1] = f2bf(v.y); o[2] = f2bf(v.z); o[3] = f2bf(v.w);
  dst[i] = o;
}

// ---------------- bf16 GEMM: C[m][n] = sum_k A[m][k]*B[n][k]  (B^T layout) ----
// 128x128 tile, BK=32, 4 waves (2x2 of 64x64), m97 structure.
__global__ __launch_bounds__(256) void gemm_bt(const short* __restrict__ A,
                                               const short* __restrict__ B,
                                               float* __restrict__ C,
                                               int M, int N, int K) {
  __shared__ __align__(16) short As[128 * 32];
  __shared__ __align__(16) short Bs[128 * 32];
  const int t = threadIdx.x, w = t >> 6, lane = t & 63;
  const int m0 = blockIdx.y * 128, n0 = blockIdx.x * 128;
  const int wr = w >> 1, wc = w & 1;
  const int l15 = lane & 15, lk = (lane >> 4) * 8;
  f32x4 acc[4][4];
#pragma unroll
  for (int a = 0; a < 4; ++a)
#pragma unroll
    for (int b = 0; b < 4; ++b) acc[a][b] = (f32x4){0.f, 0.f, 0.f, 0.f};

  // staging chunk indices: chunk c (of 512) covers elements [c*8, c*8+8) of [128][32]
  const int c0 = (w * 2) * 64 + lane;
  const int c1 = c0 + 64;
  const int rA0 = c0 >> 2, kc0 = (c0 & 3) * 8;
  const int rA1 = c1 >> 2, kc1 = (c1 & 3) * 8;

  for (int k0 = 0; k0 < K; k0 += 32) {
    __builtin_amdgcn_global_load_lds((const AS1 void*)(A + (long)(m0 + rA0) * K + k0 + kc0),
                                     (AS3 void*)(As + (w * 2) * 512), 16, 0, 0);
    __builtin_amdgcn_global_load_lds((const AS1 void*)(A + (long)(m0 + rA1) * K + k0 + kc1),
                                     (AS3 void*)(As + (w * 2 + 1) * 512), 16, 0, 0);
    __builtin_amdgcn_global_load_lds((const AS1 void*)(B + (long)(n0 + rA0) * K + k0 + kc0),
                                     (AS3 void*)(Bs + (w * 2) * 512), 16, 0, 0);
    __builtin_amdgcn_global_load_lds((const AS1 void*)(B + (long)(n0 + rA1) * K + k0 + kc1),
                                     (AS3 void*)(Bs + (w * 2 + 1) * 512), 16, 0, 0);
    __syncthreads();
    short8 af[4], bfr[4];
#pragma unroll
    for (int mi = 0; mi < 4; ++mi)
      af[mi] = *(const short8*)(As + (wr * 64 + mi * 16 + l15) * 32 + lk);
#pragma unroll
    for (int ni = 0; ni < 4; ++ni)
      bfr[ni] = *(const short8*)(Bs + (wc * 64 + ni * 16 + l15) * 32 + lk);
#pragma unroll
    for (int mi = 0; mi < 4; ++mi)
#pragma unroll
      for (int ni = 0; ni < 4; ++ni)
        acc[mi][ni] = __builtin_amdgcn_mfma_f32_16x16x32_bf16(af[mi], bfr[ni], acc[mi][ni], 0, 0, 0);
    __syncthreads();
  }
#pragma unroll
  for (int mi = 0; mi < 4; ++mi)
#pragma unroll
    for (int ni = 0; ni < 4; ++ni)
#pragma unroll
      for (int r = 0; r < 4; ++r) {
        int m = m0 + wr * 64 + mi * 16 + (lane >> 4) * 4 + r;
        int n = n0 + wc * 64 + ni * 16 + l15;
        C[(long)m * N + n] = acc[mi][ni][r];
      }
}

// ---------------- RMS norm + partial RoPE + layout shuffle --------------
// One wave per (s, head)-row. Rows: [0,S*NH) = Q, [S*NH, S*NH+S*NKH) = K, rest = V (cast only).
__global__ __launch_bounds__(256) void normrope_kernel(const float* __restrict__ QKV,
    const int* __restrict__ pos_ids, const float* __restrict__ qw,
    const float* __restrict__ kw,
    short* __restrict__ Qn, short* __restrict__ Kn, short* __restrict__ Vb) {
  const int lane = threadIdx.x & 63;
  const long row = (long)blockIdx.x * 4 + (threadIdx.x >> 6);
  const long NQ = (long)S_ * NH, NK = (long)S_ * NKH;
  const float* src;
  short* dst;
  const float* wv = nullptr;
  int s;
  float scl = 1.f;
  bool donorm = true;
  if (row < NQ) {
    s = (int)(row >> 5); int h = (int)(row & 31);
    src = QKV + (long)s * 6144 + h * 128;
    dst = Qn + ((long)h * S_ + s) * 128;
    wv = qw; scl = SCALE_;
  } else if (row < NQ + NK) {
    long r2 = row - NQ; s = (int)(r2 >> 3); int kh = (int)(r2 & 7);
    src = QKV + (long)s * 6144 + 4096 + kh * 128;
    dst = Kn + ((long)kh * S_ + s) * 128;
    wv = kw;
  } else {
    long r3 = row - NQ - NK; s = (int)(r3 >> 3); int kh = (int)(r3 & 7);
    src = QKV + (long)s * 6144 + 5120 + kh * 128;
    dst = Vb + ((long)kh * S_ + s) * 128;
    donorm = false;
  }
  float x0 = src[lane], x1 = src[lane + 64];
  if (donorm) {
    float ss = x0 * x0 + x1 * x1;
#pragma unroll
    for (int m = 1; m < 64; m <<= 1) ss += __shfl_xor(ss, m);
    float inv = rsqrtf(ss * (1.f / 128.f) + EPS_);
    x0 = x0 * inv * (wv[lane] + 1.f);
    x1 = x1 * inv * (wv[lane + 64] + 1.f);
    // partial RoPE on dims [0,64); x1 (dims [64,128)) passes through
    int pos = pos_ids[s];
    int i = lane & 31;
    float invf = expf(-logf(10000.f) * ((float)(2 * i) / 64.f));
    float f = (float)pos * invf;
    float c = cosf(f), sn = sinf(f);
    float p = __shfl_xor(x0, 32);
    x0 = (lane < 32) ? (x0 * c - p * sn) : (x0 * c + p * sn);
  }
  dst[lane] = f2bf(x0 * scl);
  dst[lane + 64] = f2bf(x1 * scl);
}

// ---------------- causal flash attention, GQA 4:1 ----------------------
// grid: (S/64, NH). 4 waves/block; wave w owns q rows [q0+16w, q0+16w+16).
__global__ __launch_bounds__(256) void attn_kernel(const short* __restrict__ Qn,
    const short* __restrict__ Kn, const short* __restrict__ Vb,
    short* __restrict__ O) {
  __shared__ __align__(16) short Ks[64 * 128];   // row-major, XOR-swizzled
  __shared__ __align__(16) short Vt[128 * 64];   // transposed [d][kv], XOR-swizzled
  __shared__ __align__(16) short Ps[4][16 * 64]; // per-wave P scratch, swizzled
  const int t = threadIdx.x, w = t >> 6, lane = t & 63;
  const int h = blockIdx.y, kh = h >> 2;
  const int q0 = blockIdx.x * 64;
  const int l15 = lane & 15, lk = (lane >> 4) * 8;

  short8 qf[4];
  {
    const short* Qh = Qn + ((long)h * S_ + q0 + w * 16) * 128;
#pragma unroll
    for (int ks = 0; ks < 4; ++ks)
      qf[ks] = *(const short8*)(Qh + l15 * 128 + ks * 32 + lk);
  }
  f32x4 o[8];
#pragma unroll
  for (int nf = 0; nf < 8; ++nf) o[nf] = (f32x4){0.f, 0.f, 0.f, 0.f};
  float mrun[4], lrun[4];
#pragma unroll
  for (int r = 0; r < 4; ++r) { mrun[r] = -1e30f; lrun[r] = 0.f; }

  const short* Kh = Kn + (long)kh * S_ * 128;
  const short* Vh = Vb + (long)kh * S_ * 128;

  for (int kv0 = 0; kv0 <= q0; kv0 += 64) {
    // ---- stage K (row-major swizzled) and V (transposed swizzled) ----
#pragma unroll
    for (int i = 0; i < 4; ++i) {
      int c = t + i * 256;               // 1024 chunks of 8 elems
      int row = c >> 4, dc = (c & 15) * 8;
      short8 kv = *(const short8*)(Kh + (long)(kv0 + row) * 128 + dc);
      int b = row * 256 + dc * 2; b ^= (row & 7) << 4;
      *(short8*)((char*)Ks + b) = kv;
      short8 vv = *(const short8*)(Vh + (long)(kv0 + row) * 128 + dc);
#pragma unroll
      for (int j = 0; j < 8; ++j) {
        int vb_ = (dc + j) * 128 + row * 2; vb_ ^= (j & 7) << 4;
        *(short*)((char*)Vt + vb_) = vv[j];
      }
    }
    __syncthreads();

    // ---- QK^T: 16x64 scores per wave ----
    f32x4 sc[4];
#pragma unroll
    for (int ni = 0; ni < 4; ++ni) sc[ni] = (f32x4){0.f, 0.f, 0.f, 0.f};
#pragma unroll
    for (int ks = 0; ks < 4; ++ks)
#pragma unroll
      for (int ni = 0; ni < 4; ++ni) {
        int row = ni * 16 + l15;
        int b = row * 256 + (ks * 32 + lk) * 2; b ^= (row & 7) << 4;
        short8 kf = *(const short8*)((const char*)Ks + b);
        sc[ni] = __builtin_amdgcn_mfma_f32_16x16x32_bf16(qf[ks], kf, sc[ni], 0, 0, 0);
      }
    // causal mask on the diagonal tile
    if (kv0 == q0) {
#pragma unroll
      for (int ni = 0; ni < 4; ++ni)
#pragma unroll
        for (int r = 0; r < 4; ++r) {
          int qm = w * 16 + (lane >> 4) * 4 + r;
          int kc = ni * 16 + l15;
          if (kc > qm) sc[ni][r] = -1e30f;
        }
    }
    // ---- online softmax (rows are lane-local across 16-lane group) ----
    short pb[4][4];
#pragma unroll
    for (int r = 0; r < 4; ++r) {
      float mx = fmaxf(fmaxf(sc[0][r], sc[1][r]), fmaxf(sc[2][r], sc[3][r]));
      mx = fmaxf(mx, __shfl_xor(mx, 1));
      mx = fmaxf(mx, __shfl_xor(mx, 2));
      mx = fmaxf(mx, __shfl_xor(mx, 4));
      mx = fmaxf(mx, __shfl_xor(mx, 8));
      float mnew = fmaxf(mrun[r], mx);
      float scale = expf(mrun[r] - mnew);
      mrun[r] = mnew;
      float ssum = 0.f;
#pragma unroll
      for (int ni = 0; ni < 4; ++ni) {
        float p = expf(sc[ni][r] - mnew);
        ssum += p;
        pb[ni][r] = f2bf(p);
      }
      ssum += __shfl_xor(ssum, 1);
      ssum += __shfl_xor(ssum, 2);
      ssum += __shfl_xor(ssum, 4);
      ssum += __shfl_xor(ssum, 8);
      lrun[r] = lrun[r] * scale + ssum;
#pragma unroll
      for (int nf = 0; nf < 8; ++nf) o[nf][r] *= scale;
    }
    // ---- P -> LDS (swizzled) to reshape into A-fragments ----
    char* pw = (char*)Ps[w];
#pragma unroll
    for (int ni = 0; ni < 4; ++ni)
#pragma unroll
      for (int r = 0; r < 4; ++r) {
        int m = (lane >> 4) * 4 + r, col = ni * 16 + l15;
        int b = m * 128 + col * 2; b ^= (m & 7) << 4;
        *(short*)(pw + b) = pb[ni][r];
      }
    // ---- PV: O(16x128) += P(16x64) * V(64x128) ----
#pragma unroll
    for (int ks2 = 0; ks2 < 2; ++ks2) {
      int bp = l15 * 128 + (ks2 * 32 + lk) * 2; bp ^= (l15 & 7) << 4;
      short8 pf = *(const short8*)(pw + bp);
#pragma unroll
      for (int nf = 0; nf < 8; ++nf) {
        int bv = (nf * 16 + l15) * 128 + (ks2 * 32 + lk) * 2; bv ^= (l15 & 7) << 4;
        short8 vf = *(const short8*)((const char*)Vt + bv);
        o[nf] = __builtin_amdgcn_mfma_f32_16x16x32_bf16(pf, vf, o[nf], 0, 0, 0);
      }
    }
    __syncthreads();
  }
  // ---- epilogue: divide by row sum, write [S][H*D] bf16 ----
#pragma unroll
  for (int nf = 0; nf < 8; ++nf)
#pragma unroll
    for (int r = 0; r < 4; ++r) {
      int m = q0 + w * 16 + (lane >> 4) * 4 + r;
      float val = o[nf][r] / lrun[r];
      O[(long)m * 4096 + h * 128 + nf * 16 + l15] = f2bf(val);
    }
}

// ---------------- launch -----------------------------------------------
extern "C" void kernel_launch(void* const* d_in, const int* in_sizes, int n_in,
                              void* d_out, int out_size, void* d_ws, size_t ws_size,
                              hipStream_t stream) {
  const float* hidden = (const float*)d_in[0];
  const float* Wq = (const float*)d_in[1];
  const float* Wk = (const float*)d_in[2];
  const float* Wv = (const float*)d_in[3];
  const float* Wo = (const float*)d_in[4];
  const float* qw = (const float*)d_in[5];
  const float* kw = (const float*)d_in[6];
  const int* pos = (const int*)d_in[7];
  float* out = (float*)d_out;

  char* ws = (char*)d_ws;
  // workspace layout (bytes)
  short* hid_bf  = (short*)(ws + 0);              // 16 MB  (dead after GEMM1)
  short* Wqkv_bf = (short*)(ws + 16777216L);      // 48 MB
  short* Wo_bf   = (short*)(ws + 67108864L);      // 32 MB
  float* QKVf    = (float*)(ws + 100663296L);     // 48 MB
  short* Qn      = (short*)(ws + 150994944L);     // 16 MB
  short* Kn      = (short*)(ws + 167772160L);     // 4 MB
  short* Vb      = (short*)(ws + 171966464L);     // 4 MB
  short* AO      = hid_bf;                        // alias: reuse dead region

  auto cast = [&](const float* s_, short* d_, long n) {
    int n4 = (int)(n / 4);
    cast_bf16_kernel<<<(n4 + 255) / 256, 256, 0, stream>>>((const float4*)s_, (short4v*)d_, n4);
  };
  cast(hidden, hid_bf, (long)S_ * HID_);
  cast(Wq, Wqkv_bf, (long)4096 * 4096);
  cast(Wk, Wqkv_bf + (long)4096 * 4096, (long)1024 * 4096);
  cast(Wv, Wqkv_bf + (long)5120 * 4096, (long)1024 * 4096);
  cast(Wo, Wo_bf, (long)4096 * 4096);

  // QKV = hidden @ [Wq;Wk;Wv]^T : M=2048, N=6144, K=4096
  gemm_bt<<<dim3(6144 / 128, S_ / 128), 256, 0, stream>>>(hid_bf, Wqkv_bf, QKVf, S_, 6144, HID_);

  // norm + rope + layout: rows = S*(NH + NKH + NKH) = 98304, 4 rows/block
  normrope_kernel<<<(S_ * (NH + 2 * NKH)) / 4, 256, 0, stream>>>(QKVf, pos, qw, kw, Qn, Kn, Vb);

  // attention: grid (S/64, NH)
  attn_kernel<<<dim3(S_ / 64, NH), 256, 0, stream>>>(Qn, Kn, Vb, AO);

  // out = AO @ Wo^T : M=2048, N=4096, K=4096  (fp32 out)
  gemm_bt<<<dim3(HID_ / 128, S_ / 128), 256, 0, stream>>>(AO, Wo_bf, out, S_, HID_, HID_);
}

// Round 2
// 599.170 us; speedup vs baseline: 1.4687x; 1.4687x over previous
//
#include <hip/hip_runtime.h>
#include <hip/hip_bf16.h>

#define AS1 __attribute__((address_space(1)))
#define AS3 __attribute__((address_space(3)))

typedef __attribute__((ext_vector_type(8))) short short8;
typedef __attribute__((ext_vector_type(4))) short short4v;
typedef __attribute__((ext_vector_type(4))) float f32x4;

constexpr int S_ = 2048;
constexpr int HID_ = 4096;
constexpr int NH = 32;       // q heads
constexpr int NKH = 8;       // kv heads
constexpr float EPS_ = 1e-5f;
constexpr float SCALE_ = 0.08838834764831845f;  // 128^-0.5

__device__ __forceinline__ short f2bf(float f) {
  __hip_bfloat16 h = __float2bfloat16(f);
  return *reinterpret_cast<short*>(&h);
}

// ---------------- fp32 -> bf16 cast (vectorized) ----------------
__global__ __launch_bounds__(256) void cast_bf16_kernel(const float4* __restrict__ src,
                                                        short4v* __restrict__ dst, int n4) {
  int i = blockIdx.x * 256 + threadIdx.x;
  if (i >= n4) return;
  float4 v = src[i];
  short4v o;
  o[0] = f2bf(v.x); o[1] = f2bf(v.y); o[2] = f2bf(v.z); o[3] = f2bf(v.w);
  dst[i] = o;
}

// ---------------- bf16 GEMM: C[m][n] = sum_k A[m][k]*B[n][k]  (B^T layout) ----
__global__ __launch_bounds__(256) void gemm_bt(const short* __restrict__ A,
                                               const short* __restrict__ B,
                                               float* __restrict__ C,
                                               int M, int N, int K) {
  __shared__ __align__(16) short As[128 * 32];
  __shared__ __align__(16) short Bs[128 * 32];
  const int t = threadIdx.x, w = t >> 6, lane = t & 63;
  const int m0 = blockIdx.y * 128, n0 = blockIdx.x * 128;
  const int wr = w >> 1, wc = w & 1;
  const int l15 = lane & 15, lk = (lane >> 4) * 8;
  f32x4 acc[4][4];
#pragma unroll
  for (int a = 0; a < 4; ++a)
#pragma unroll
    for (int b = 0; b < 4; ++b) acc[a][b] = (f32x4){0.f, 0.f, 0.f, 0.f};

  const int c0 = (w * 2) * 64 + lane;
  const int c1 = c0 + 64;
  const int rA0 = c0 >> 2, kc0 = (c0 & 3) * 8;
  const int rA1 = c1 >> 2, kc1 = (c1 & 3) * 8;

  for (int k0 = 0; k0 < K; k0 += 32) {
    __builtin_amdgcn_global_load_lds((const AS1 void*)(A + (long)(m0 + rA0) * K + k0 + kc0),
                                     (AS3 void*)(As + (w * 2) * 512), 16, 0, 0);
    __builtin_amdgcn_global_load_lds((const AS1 void*)(A + (long)(m0 + rA1) * K + k0 + kc1),
                                     (AS3 void*)(As + (w * 2 + 1) * 512), 16, 0, 0);
    __builtin_amdgcn_global_load_lds((const AS1 void*)(B + (long)(n0 + rA0) * K + k0 + kc0),
                                     (AS3 void*)(Bs + (w * 2) * 512), 16, 0, 0);
    __builtin_amdgcn_global_load_lds((const AS1 void*)(B + (long)(n0 + rA1) * K + k0 + kc1),
                                     (AS3 void*)(Bs + (w * 2 + 1) * 512), 16, 0, 0);
    __syncthreads();
    short8 af[4], bfr[4];
#pragma unroll
    for (int mi = 0; mi < 4; ++mi)
      af[mi] = *(const short8*)(As + (wr * 64 + mi * 16 + l15) * 32 + lk);
#pragma unroll
    for (int ni = 0; ni < 4; ++ni)
      bfr[ni] = *(const short8*)(Bs + (wc * 64 + ni * 16 + l15) * 32 + lk);
#pragma unroll
    for (int mi = 0; mi < 4; ++mi)
#pragma unroll
      for (int ni = 0; ni < 4; ++ni)
        acc[mi][ni] = __builtin_amdgcn_mfma_f32_16x16x32_bf16(af[mi], bfr[ni], acc[mi][ni], 0, 0, 0);
    __syncthreads();
  }
#pragma unroll
  for (int mi = 0; mi < 4; ++mi)
#pragma unroll
    for (int ni = 0; ni < 4; ++ni)
#pragma unroll
      for (int r = 0; r < 4; ++r) {
        int m = m0 + wr * 64 + mi * 16 + (lane >> 4) * 4 + r;
        int n = n0 + wc * 64 + ni * 16 + l15;
        C[(long)m * N + n] = acc[mi][ni][r];
      }
}

// ---------------- RMS norm + partial RoPE (Q and K only) --------------
__global__ __launch_bounds__(256) void normrope_kernel(const float* __restrict__ QKV,
    const int* __restrict__ pos_ids, const float* __restrict__ qw,
    const float* __restrict__ kw,
    short* __restrict__ Qn, short* __restrict__ Kn) {
  const int lane = threadIdx.x & 63;
  const long row = (long)blockIdx.x * 4 + (threadIdx.x >> 6);
  const long NQ = (long)S_ * NH;
  const float* src;
  short* dst;
  const float* wv;
  int s;
  float scl = 1.f;
  if (row < NQ) {
    s = (int)(row >> 5); int h = (int)(row & 31);
    src = QKV + (long)s * 6144 + h * 128;
    dst = Qn + ((long)h * S_ + s) * 128;
    wv = qw; scl = SCALE_;
  } else {
    long r2 = row - NQ; s = (int)(r2 >> 3); int kh = (int)(r2 & 7);
    src = QKV + (long)s * 6144 + 4096 + kh * 128;
    dst = Kn + ((long)kh * S_ + s) * 128;
    wv = kw;
  }
  float x0 = src[lane], x1 = src[lane + 64];
  float ss = x0 * x0 + x1 * x1;
#pragma unroll
  for (int m = 1; m < 64; m <<= 1) ss += __shfl_xor(ss, m);
  float inv = rsqrtf(ss * (1.f / 128.f) + EPS_);
  x0 = x0 * inv * (wv[lane] + 1.f);
  x1 = x1 * inv * (wv[lane + 64] + 1.f);
  int pos = pos_ids[s];
  int i = lane & 31;
  float invf = expf(-logf(10000.f) * ((float)(2 * i) / 64.f));
  float f = (float)pos * invf;
  float c = cosf(f), sn = sinf(f);
  float p = __shfl_xor(x0, 32);
  x0 = (lane < 32) ? (x0 * c - p * sn) : (x0 * c + p * sn);
  dst[lane] = f2bf(x0 * scl);
  dst[lane + 64] = f2bf(x1 * scl);
}

// ---------------- V transpose: QKVf V-cols -> Vt[kh][128][S] bf16 ------
__global__ __launch_bounds__(256) void vtrans_kernel(const float* __restrict__ QKV,
                                                     short* __restrict__ Vt) {
  __shared__ __align__(16) float lt[64][68];
  const int t = threadIdx.x;
  const int s0 = blockIdx.x * 64, d0 = blockIdx.y * 64, kh = blockIdx.z;
  const float* src = QKV + (long)s0 * 6144 + 5120 + kh * 128 + d0;
#pragma unroll
  for (int i = 0; i < 4; ++i) {
    int idx = t + i * 256;
    int r = idx >> 4, c4 = (idx & 15) * 4;
    float4 v = *(const float4*)(src + (long)r * 6144 + c4);
    *(float4*)&lt[r][c4] = v;
  }
  __syncthreads();
  int d = t >> 2, seg = (t & 3) * 16;
  short* dst = Vt + ((long)kh * 128 + d0 + d) * S_ + s0 + seg;
  short8 a, b2;
#pragma unroll
  for (int j = 0; j < 8; ++j) a[j] = f2bf(lt[seg + j][d]);
#pragma unroll
  for (int j = 0; j < 8; ++j) b2[j] = f2bf(lt[seg + 8 + j][d]);
  *(short8*)dst = a;
  *(short8*)(dst + 8) = b2;
}

// ---------------- causal flash attention, GQA 4:1 ----------------------
// 512 blocks (qt descending for LPT balance), 8 waves, QBLK=128, KVBLK=64.
__global__ __launch_bounds__(512, 2) void attn_kernel(const short* __restrict__ Qn,
    const short* __restrict__ Kn, const short* __restrict__ Vt,
    short* __restrict__ O) {
  __shared__ __align__(16) short Ks[64 * 128];   // [kv][d], 16B-chunk XOR-swizzled
  __shared__ __align__(16) short Vs[128 * 64];   // [d][kv], 16B-chunk XOR-swizzled
  __shared__ __align__(16) short Ps[8][16 * 64]; // per-wave P, swizzled
  const int t = threadIdx.x, w = t >> 6, lane = t & 63;
  const int b = blockIdx.x;
  const int h = b & 31, qt = 15 - (b >> 5);
  const int kh = h >> 2;
  const int q0 = qt * 128;
  const int l15 = lane & 15, lk = (lane >> 4) * 8;

  // Q fragments for this wave's 16 rows
  short8 qf[4];
  {
    const short* Qh = Qn + ((long)h * S_ + q0 + w * 16) * 128;
#pragma unroll
    for (int ks = 0; ks < 4; ++ks)
      qf[ks] = *(const short8*)(Qh + l15 * 128 + ks * 32 + lk);
  }
  f32x4 o[8];
#pragma unroll
  for (int nf = 0; nf < 8; ++nf) o[nf] = (f32x4){0.f, 0.f, 0.f, 0.f};
  float mrun[4], lrun[4];
#pragma unroll
  for (int r = 0; r < 4; ++r) { mrun[r] = -1e30f; lrun[r] = 0.f; }

  const short* Khp = Kn + (long)kh * S_ * 128;
  const short* Vtp = Vt + (long)kh * 128 * S_;

  // staging lane geometry (pre-swizzled global source, linear LDS dest)
  const int krr = w * 8 + (lane >> 4);   // + j*4  (K rows, 4 rows/instr)
  const int kc = lane & 15;              // K 16B-chunk within row (16 chunks)
  const int vdd = w * 16 + (lane >> 3);  // + j*8  (V d-rows, 8 rows/instr)
  const int vc = lane & 7;               // V 16B-chunk within row (8 chunks)
  char* pw = (char*)Ps[w];
  const int mrow = (lane >> 4) * 4;

  for (int kv0 = 0; kv0 < q0 + 128; kv0 += 64) {
    // ---- stage K [64][128] and V^T [128][64] via global_load_lds ----
#pragma unroll
    for (int j = 0; j < 2; ++j) {
      int rr = krr + j * 4;
      __builtin_amdgcn_global_load_lds(
          (const AS1 void*)(Khp + (long)(kv0 + rr) * 128 + ((kc ^ (rr & 7)) * 8)),
          (AS3 void*)(Ks + (w * 8 + j * 4) * 128 + lane * 8), 16, 0, 0);
    }
#pragma unroll
    for (int j = 0; j < 2; ++j) {
      int d = vdd + j * 8;
      __builtin_amdgcn_global_load_lds(
          (const AS1 void*)(Vtp + (long)d * S_ + kv0 + ((vc ^ (d & 7)) * 8)),
          (AS3 void*)(Vs + (w * 16 + j * 8) * 64 + lane * 8), 16, 0, 0);
    }
    __syncthreads();

    const bool active = (kv0 <= q0 + w * 16 + 15);
    if (active) {
      // ---- QK^T: 16x64 scores ----
      f32x4 sc[4];
#pragma unroll
      for (int ni = 0; ni < 4; ++ni) sc[ni] = (f32x4){0.f, 0.f, 0.f, 0.f};
#pragma unroll
      for (int ks = 0; ks < 4; ++ks)
#pragma unroll
        for (int ni = 0; ni < 4; ++ni) {
          int row = ni * 16 + l15;
          int bb = row * 256 + (ks * 32 + lk) * 2; bb ^= (row & 7) << 4;
          short8 kf = *(const short8*)((const char*)Ks + bb);
          sc[ni] = __builtin_amdgcn_mfma_f32_16x16x32_bf16(qf[ks], kf, sc[ni], 0, 0, 0);
        }
      // causal mask (only tiles straddling/past this wave's diagonal)
      if (kv0 + 64 > q0 + w * 16) {
#pragma unroll
        for (int ni = 0; ni < 4; ++ni)
#pragma unroll
          for (int r = 0; r < 4; ++r) {
            int qm = q0 + w * 16 + mrow + r;
            int kcol = kv0 + ni * 16 + l15;
            if (kcol > qm) sc[ni][r] = -1e30f;
          }
      }
      // ---- online softmax (kv spread across 16-lane group) ----
      short pb[4][4];
#pragma unroll
      for (int r = 0; r < 4; ++r) {
        float mx = fmaxf(fmaxf(sc[0][r], sc[1][r]), fmaxf(sc[2][r], sc[3][r]));
        mx = fmaxf(mx, __shfl_xor(mx, 1));
        mx = fmaxf(mx, __shfl_xor(mx, 2));
        mx = fmaxf(mx, __shfl_xor(mx, 4));
        mx = fmaxf(mx, __shfl_xor(mx, 8));
        float mnew = fmaxf(mrun[r], mx);
        float scale = expf(mrun[r] - mnew);
        mrun[r] = mnew;
        float ssum = 0.f;
#pragma unroll
        for (int ni = 0; ni < 4; ++ni) {
          float p = expf(sc[ni][r] - mnew);
          ssum += p;
          pb[ni][r] = f2bf(p);
        }
        ssum += __shfl_xor(ssum, 1);
        ssum += __shfl_xor(ssum, 2);
        ssum += __shfl_xor(ssum, 4);
        ssum += __shfl_xor(ssum, 8);
        lrun[r] = lrun[r] * scale + ssum;
#pragma unroll
        for (int nf = 0; nf < 8; ++nf) o[nf][r] *= scale;
      }
      // ---- P -> per-wave LDS (swizzled); wave-local, no barrier ----
#pragma unroll
      for (int ni = 0; ni < 4; ++ni)
#pragma unroll
        for (int r = 0; r < 4; ++r) {
          int m = mrow + r;
          int bb = m * 128 + (ni * 16 + l15) * 2; bb ^= (m & 7) << 4;
          *(short*)(pw + bb) = pb[ni][r];
        }
      // ---- PV: O(16x128) += P(16x64) * V^T fragments ----
#pragma unroll
      for (int ks2 = 0; ks2 < 2; ++ks2) {
        int bp = l15 * 128 + (ks2 * 32 + lk) * 2; bp ^= (l15 & 7) << 4;
        short8 pf = *(const short8*)(pw + bp);
#pragma unroll
        for (int nf = 0; nf < 8; ++nf) {
          int bv = (nf * 16 + l15) * 128 + (ks2 * 32 + lk) * 2; bv ^= (l15 & 7) << 4;
          short8 vf = *(const short8*)((const char*)Vs + bv);
          o[nf] = __builtin_amdgcn_mfma_f32_16x16x32_bf16(pf, vf, o[nf], 0, 0, 0);
        }
      }
    }
    __syncthreads();
  }
  // ---- epilogue ----
#pragma unroll
  for (int r = 0; r < 4; ++r) {
    float invl = 1.f / lrun[r];
    int m = q0 + w * 16 + mrow + r;
#pragma unroll
    for (int nf = 0; nf < 8; ++nf)
      O[(long)m * 4096 + h * 128 + nf * 16 + l15] = f2bf(o[nf][r] * invl);
  }
}

// ---------------- launch -----------------------------------------------
extern "C" void kernel_launch(void* const* d_in, const int* in_sizes, int n_in,
                              void* d_out, int out_size, void* d_ws, size_t ws_size,
                              hipStream_t stream) {
  const float* hidden = (const float*)d_in[0];
  const float* Wq = (const float*)d_in[1];
  const float* Wk = (const float*)d_in[2];
  const float* Wv = (const float*)d_in[3];
  const float* Wo = (const float*)d_in[4];
  const float* qw = (const float*)d_in[5];
  const float* kw = (const float*)d_in[6];
  const int* pos = (const int*)d_in[7];
  float* out = (float*)d_out;

  char* ws = (char*)d_ws;
  short* hid_bf  = (short*)(ws + 0);              // 16 MB (dead after GEMM1)
  short* Wqkv_bf = (short*)(ws + 16777216L);      // 48 MB
  short* Wo_bf   = (short*)(ws + 67108864L);      // 32 MB
  float* QKVf    = (float*)(ws + 100663296L);     // 48 MB
  short* Qn      = (short*)(ws + 150994944L);     // 16 MB
  short* Kn      = (short*)(ws + 167772160L);     // 4 MB
  short* Vt      = (short*)(ws + 171966464L);     // 4 MB (transposed V)
  short* AO      = hid_bf;                        // alias

  auto cast = [&](const float* s_, short* d_, long n) {
    int n4 = (int)(n / 4);
    cast_bf16_kernel<<<(n4 + 255) / 256, 256, 0, stream>>>((const float4*)s_, (short4v*)d_, n4);
  };
  cast(hidden, hid_bf, (long)S_ * HID_);
  cast(Wq, Wqkv_bf, (long)4096 * 4096);
  cast(Wk, Wqkv_bf + (long)4096 * 4096, (long)1024 * 4096);
  cast(Wv, Wqkv_bf + (long)5120 * 4096, (long)1024 * 4096);
  cast(Wo, Wo_bf, (long)4096 * 4096);

  // QKV = hidden @ [Wq;Wk;Wv]^T : M=2048, N=6144, K=4096
  gemm_bt<<<dim3(6144 / 128, S_ / 128), 256, 0, stream>>>(hid_bf, Wqkv_bf, QKVf, S_, 6144, HID_);

  // norm + rope (Q,K): rows = S*(NH + NKH) = 81920, 4 rows/block
  normrope_kernel<<<(S_ * (NH + NKH)) / 4, 256, 0, stream>>>(QKVf, pos, qw, kw, Qn, Kn);

  // V transpose+cast: Vt[kh][128][S]
  vtrans_kernel<<<dim3(S_ / 64, 2, NKH), 256, 0, stream>>>(QKVf, Vt);

  // attention: 512 blocks, qt descending
  attn_kernel<<<dim3(512), 512, 0, stream>>>(Qn, Kn, Vt, AO);

  // out = AO @ Wo^T : M=2048, N=4096, K=4096 (fp32 out)
  gemm_bt<<<dim3(HID_ / 128, S_ / 128), 256, 0, stream>>>(AO, Wo_bf, out, S_, HID_, HID_);
}